// Round 1
// baseline (6021.109 us; speedup 1.0000x reference)
//
#include <hip/hip_runtime.h>
#include <stdint.h>
#include <stddef.h>

// LSTM 2-layer, B=64,T=1024,D=64,H=256 -> fc(mean_t h)  [MI355X gfx950]
// Strategy: input GEMMs lifted out (MFMA), recurrent scan = 4 WGs (16 batch
// each, M=16 MFMA), Whh resident in VGPR(48 frags)+LDS(16 frags) per wave.
// Chunked (CH=256) to keep ws under ~43MB; scan state persisted in ws.

#define T_LEN 1024
#define NB    64
#define DIN   64
#define HID   256
#define G4    1024
#define CH    256
#define NCH   (T_LEN/CH)

typedef __attribute__((ext_vector_type(8))) short  bf16x8;
typedef __attribute__((ext_vector_type(4))) float  f32x4;

__device__ __forceinline__ ushort f2b(float x) {      // fp32 -> bf16 RNE
  uint u = __float_as_uint(x);
  uint r = (u + 0x7fffu + ((u >> 16) & 1u)) >> 16;
  return (ushort)r;
}
__device__ __forceinline__ float b2f(uint u16) {      // bf16 -> fp32 exact
  return __uint_as_float(u16 << 16);
}
__device__ __forceinline__ float sigm(float x) {
  float e = __expf(-x);
  return __builtin_amdgcn_rcpf(1.f + e);
}
__device__ __forceinline__ float tanhf_fast(float x) {
  float e = __expf(-2.f * x);
  return (1.f - e) * __builtin_amdgcn_rcpf(1.f + e);
}

// ---------------- weight convert (fp32->bf16) + bias sums -----------------
__global__ void convert_weights(const float* __restrict__ Wih0, const float* __restrict__ Whh0,
                                const float* __restrict__ Wih1, const float* __restrict__ Whh1,
                                const float* __restrict__ bih0, const float* __restrict__ bhh0,
                                const float* __restrict__ bih1, const float* __restrict__ bhh1,
                                ushort* __restrict__ Wb, float* __restrict__ bsum)
{
  int i = blockIdx.x * 256 + threadIdx.x;
  const int n0 = G4*DIN, n1 = G4*HID;
  const int total = n0 + 3*n1;                 // 851968
  if (i < total) {
    float v;
    if (i < n0)           v = Wih0[i];
    else if (i < n0+n1)   v = Whh0[i-n0];
    else if (i < n0+2*n1) v = Wih1[i-n0-n1];
    else                  v = Whh1[i-n0-2*n1];
    Wb[i] = f2b(v);
  }
  if (i < G4)        bsum[i] = bih0[i] + bhh0[i];
  else if (i < 2*G4) bsum[i] = bih1[i-G4] + bhh1[i-G4];
}

// ------------- input-projection GEMM: gx[t] = A_t @ W^T + bias -------------
// SRC=0: A = x fp32 [B][T][DIN]  (KDIM=64)
// SRC=1: A = hs0c bf16 [CH][64][HID] (KDIM=256)
// Output gxF bf16 in MFMA-fragment order: [tloc][ct 0..63][grp 0..3][lane][r]
template<int SRC, int KDIM>
__global__ __launch_bounds__(512, 2) void gemm_gates(
    const void* __restrict__ Asrc, const ushort* __restrict__ W,
    const float* __restrict__ bias, ushort* __restrict__ gxF, int t0)
{
  __shared__ __align__(16) char sA[64 * KDIM * 2];
  const int tid  = threadIdx.x;
  const int wave = tid >> 6, lane = tid & 63;
  const int l15 = lane & 15, lhi = lane >> 4;
  const int tloc = blockIdx.x;
  const int t = t0 + tloc;

  if (SRC == 0) {
    const float* x = (const float*)Asrc;
    int b = tid >> 3, k8 = (tid & 7) * 8;
    const float* xp = x + ((size_t)b * T_LEN + t) * DIN + k8;
    float4 v0 = *(const float4*)xp;
    float4 v1 = *(const float4*)(xp + 4);
    bf16x8 pv;
    pv[0]=(short)f2b(v0.x); pv[1]=(short)f2b(v0.y); pv[2]=(short)f2b(v0.z); pv[3]=(short)f2b(v0.w);
    pv[4]=(short)f2b(v1.x); pv[5]=(short)f2b(v1.y); pv[6]=(short)f2b(v1.z); pv[7]=(short)f2b(v1.w);
    uint bo = (uint)(b * KDIM * 2 + k8 * 2) ^ ((uint)(b & 7) << 4);
    *reinterpret_cast<bf16x8*>(&sA[bo]) = pv;
  } else {
    const ushort* hs = (const ushort*)Asrc;
    int b = tid >> 3, kb = tid & 7;
    #pragma unroll
    for (int j = 0; j < KDIM/64; ++j) {
      int k8 = (kb + j*8) * 8;
      bf16x8 v = *reinterpret_cast<const bf16x8*>(hs + ((size_t)tloc * 64 + b) * KDIM + k8);
      uint bo = (uint)(b * KDIM * 2 + k8 * 2) ^ ((uint)(b & 7) << 4);
      *reinterpret_cast<bf16x8*>(&sA[bo]) = v;
    }
  }
  __syncthreads();

  float bb[8];
  #pragma unroll
  for (int i = 0; i < 8; ++i) bb[i] = bias[(wave*8 + i)*16 + l15];

  f32x4 acc[4][8];
  #pragma unroll
  for (int mt = 0; mt < 4; ++mt)
    #pragma unroll
    for (int i = 0; i < 8; ++i) {
      acc[mt][i][0] = bb[i]; acc[mt][i][1] = bb[i];
      acc[mt][i][2] = bb[i]; acc[mt][i][3] = bb[i];
    }

  #pragma unroll
  for (int kc = 0; kc < KDIM/32; ++kc) {
    const int koff = kc*32 + lhi*8;
    bf16x8 wf[8];
    #pragma unroll
    for (int i = 0; i < 8; ++i)
      wf[i] = *reinterpret_cast<const bf16x8*>(W + (size_t)((wave*8 + i)*16 + l15) * KDIM + koff);
    #pragma unroll
    for (int mt = 0; mt < 4; ++mt) {
      const int row = mt*16 + l15;
      const uint bo = (uint)(row * KDIM * 2 + koff * 2) ^ ((uint)(row & 7) << 4);
      bf16x8 a = *reinterpret_cast<const bf16x8*>(&sA[bo]);
      #pragma unroll
      for (int i = 0; i < 8; ++i)
        acc[mt][i] = __builtin_amdgcn_mfma_f32_16x16x32_bf16(a, wf[i], acc[mt][i], 0, 0, 0);
    }
  }

  #pragma unroll
  for (int mt = 0; mt < 4; ++mt)
    #pragma unroll
    for (int i = 0; i < 8; ++i) {
      const int ct = wave*8 + i;
      uint2 q;
      q.x = (uint)f2b(acc[mt][i][0]) | ((uint)f2b(acc[mt][i][1]) << 16);
      q.y = (uint)f2b(acc[mt][i][2]) | ((uint)f2b(acc[mt][i][3]) << 16);
      *reinterpret_cast<uint2*>(gxF + ((size_t)((tloc*64 + ct)*4 + mt)*64 + lane)*4) = q;
    }
}

// --------------------------- recurrent scan -------------------------------
// 4 WGs (one per 16-batch group), 8 waves. Wave w owns hidden units
// [32w,32w+32): 8 col-tiles tl=g*2+half -> gate col0 = g*256 + 32w + 16*half.
// Whh frags: kc 0..5 in VGPRs (192 regs), kc 6..7 in LDS (128KB).
// h double-buffered in LDS (2x8KB), XOR-swizzled to kill 32-way conflicts.
template<int LAYER>
__global__ __launch_bounds__(512, 2) void lstm_scan(
    const ushort* __restrict__ gxF, const ushort* __restrict__ Whh,
    ushort* __restrict__ hs_out,     // LAYER0: [CH][64][256] bf16
    float* __restrict__ hsum_out,    // LAYER1: [64][256]
    ushort* __restrict__ h_state,    // [4][4096] ushort (raw swizzled 8KB/grp)
    float* __restrict__ c_state,     // [4][512][8]
    float* __restrict__ hacc_state,  // LAYER1: [4][512][8]
    int t0)
{
  __shared__ __align__(16) char sW[131072];
  __shared__ __align__(16) char sH[16384];

  const int tid = threadIdx.x;
  const int wave = tid >> 6, lane = tid & 63;
  const int l15 = lane & 15, lhi = lane >> 4;
  const int grp = blockIdx.x;

  // ---- load resident weight fragments (once) ----
  bf16x8 wv[8][6];
  #pragma unroll
  for (int tl = 0; tl < 8; ++tl) {
    const int g = tl >> 1, hf = tl & 1;
    const int row = g*256 + wave*32 + hf*16 + l15;
    const ushort* wp = Whh + (size_t)row * HID;
    #pragma unroll
    for (int kc = 0; kc < 6; ++kc)
      wv[tl][kc] = *reinterpret_cast<const bf16x8*>(wp + kc*32 + lhi*8);
    #pragma unroll
    for (int kc = 6; kc < 8; ++kc) {
      bf16x8 w = *reinterpret_cast<const bf16x8*>(wp + kc*32 + lhi*8);
      *reinterpret_cast<bf16x8*>(&sW[((wave*16 + (kc-6)*8 + tl) << 10) + lane*16]) = w;
    }
  }

  // ---- init / restore h in LDS ----
  if (t0 == 0) {
    for (int i = tid; i < 4096; i += 512) reinterpret_cast<float*>(sH)[i] = 0.f;
  } else {
    const uint* src = reinterpret_cast<const uint*>(h_state) + grp*2048;
    for (int i = tid; i < 2048; i += 512) reinterpret_cast<uint*>(sH)[i] = src[i];
  }

  float c[8], hacc[8];
  if (t0 == 0) {
    #pragma unroll
    for (int i = 0; i < 8; ++i) { c[i] = 0.f; hacc[i] = 0.f; }
  } else {
    const float* cs = c_state + ((size_t)grp*512 + tid)*8;
    #pragma unroll
    for (int i = 0; i < 8; ++i) c[i] = cs[i];
    if (LAYER == 1) {
      const float* ha = hacc_state + ((size_t)grp*512 + tid)*8;
      #pragma unroll
      for (int i = 0; i < 8; ++i) hacc[i] = ha[i];
    } else {
      #pragma unroll
      for (int i = 0; i < 8; ++i) hacc[i] = 0.f;
    }
  }

  // ---- prefetch gx for tloc=0 ----
  uint2 gxb[8];
  #pragma unroll
  for (int tl = 0; tl < 8; ++tl) {
    const int g = tl >> 1, hf = tl & 1;
    const int ct = g*16 + wave*2 + hf;
    gxb[tl] = *reinterpret_cast<const uint2*>(gxF + ((size_t)(ct*4 + grp)*64 + lane)*4);
  }

  __syncthreads();

  int cur = 0;
  for (int tloc = 0; tloc < CH; ++tloc) {
    const char* hrd = &sH[cur * 8192];
    char* hwr = &sH[(cur ^ 1) * 8192];
    #pragma unroll
    for (int hf = 0; hf < 2; ++hf) {
      f32x4 acc[4];
      #pragma unroll
      for (int g = 0; g < 4; ++g) {          // acc init = gx (incl. bias)
        uint2 q = gxb[g*2 + hf];
        acc[g][0] = b2f(q.x & 0xffffu);
        acc[g][1] = b2f(q.x >> 16);
        acc[g][2] = b2f(q.y & 0xffffu);
        acc[g][3] = b2f(q.y >> 16);
      }
      if (hf == 1) {                         // prefetch next step's gx early
        int tln = tloc + 1; if (tln >= CH) tln = 0;
        #pragma unroll
        for (int tl = 0; tl < 8; ++tl) {
          const int g = tl >> 1, h2 = tl & 1;
          const int ct = g*16 + wave*2 + h2;
          gxb[tl] = *reinterpret_cast<const uint2*>(
              gxF + ((size_t)((tln*64 + ct)*4 + grp)*64 + lane)*4);
        }
      }
      #pragma unroll
      for (int kc = 0; kc < 8; ++kc) {       // gates += h @ Whh^T
        const int koff = kc*32 + lhi*8;
        const uint abo = (uint)(l15*512 + koff*2) ^ ((uint)(l15 & 7) << 4);
        bf16x8 a = *reinterpret_cast<const bf16x8*>(hrd + abo);
        if (kc < 6) {
          #pragma unroll
          for (int g = 0; g < 4; ++g)
            acc[g] = __builtin_amdgcn_mfma_f32_16x16x32_bf16(a, wv[g*2+hf][kc], acc[g], 0, 0, 0);
        } else {
          #pragma unroll
          for (int g = 0; g < 4; ++g) {
            bf16x8 w = *reinterpret_cast<const bf16x8*>(
                &sW[((wave*16 + (kc-6)*8 + g*2+hf) << 10) + lane*16]);
            acc[g] = __builtin_amdgcn_mfma_f32_16x16x32_bf16(a, w, acc[g], 0, 0, 0);
          }
        }
      }
      const int ubase = wave*32 + hf*16 + l15;
      #pragma unroll
      for (int r = 0; r < 4; ++r) {          // activations + state update
        float vi = acc[0][r], vf = acc[1][r], vg = acc[2][r], vo = acc[3][r];
        float ig = sigm(vi), fg = sigm(vf), gg = tanhf_fast(vg), og = sigm(vo);
        const int ci = hf*4 + r;
        float cn = __builtin_fmaf(fg, c[ci], ig*gg);
        c[ci] = cn;
        float h = og * tanhf_fast(cn);
        if (LAYER == 1) hacc[ci] += h;
        const int b = lhi*4 + r;
        const uint wb = (uint)(b*512 + ubase*2) ^ ((uint)(b & 7) << 4);
        *reinterpret_cast<ushort*>(hwr + wb) = f2b(h);
        if (LAYER == 0)
          hs_out[((size_t)tloc*64 + grp*16 + b)*256 + ubase] = f2b(h);
      }
    }
    __syncthreads();
    cur ^= 1;
  }

  // ---- save state ----
  {
    uint* dst = reinterpret_cast<uint*>(h_state) + grp*2048;
    const uint* src = reinterpret_cast<const uint*>(&sH[cur*8192]);
    for (int i = tid; i < 2048; i += 512) dst[i] = src[i];
    float* cs = c_state + ((size_t)grp*512 + tid)*8;
    #pragma unroll
    for (int i = 0; i < 8; ++i) cs[i] = c[i];
    if (LAYER == 1) {
      float* ha = hacc_state + ((size_t)grp*512 + tid)*8;
      #pragma unroll
      for (int i = 0; i < 8; ++i) ha[i] = hacc[i];
      #pragma unroll
      for (int hf = 0; hf < 2; ++hf)
        #pragma unroll
        for (int r = 0; r < 4; ++r) {
          const int b = lhi*4 + r, u = wave*32 + hf*16 + l15;
          hsum_out[((size_t)grp*16 + b)*256 + u] = hacc[hf*4 + r];
        }
    }
  }
}

// ------------------------------- final fc ---------------------------------
__global__ void fc_kernel(const float* __restrict__ hsum, const float* __restrict__ Wfc,
                          const float* __restrict__ bfc, float* __restrict__ out)
{
  int tid = threadIdx.x;
  if (tid < 640) {
    int b = tid / 10, o = tid - b*10;
    const float* hp = hsum + b*256;
    const float* wp = Wfc + o*256;
    float s = 0.f;
    #pragma unroll 8
    for (int u = 0; u < 256; ++u) s = __builtin_fmaf(hp[u], wp[u], s);
    out[tid] = s * (1.f/1024.f) + bfc[o];
  }
}

extern "C" void kernel_launch(void* const* d_in, const int* in_sizes, int n_in,
                              void* d_out, int out_size, void* d_ws, size_t ws_size,
                              hipStream_t stream)
{
  const float* x    = (const float*)d_in[0];
  const float* Wih0 = (const float*)d_in[1];
  const float* Whh0 = (const float*)d_in[2];
  const float* bih0 = (const float*)d_in[3];
  const float* bhh0 = (const float*)d_in[4];
  const float* Wih1 = (const float*)d_in[5];
  const float* Whh1 = (const float*)d_in[6];
  const float* bih1 = (const float*)d_in[7];
  const float* bhh1 = (const float*)d_in[8];
  const float* Wfc  = (const float*)d_in[9];
  const float* bfc  = (const float*)d_in[10];
  float* out = (float*)d_out;
  char* ws = (char*)d_ws;

  // ws layout (total ~42.3 MB)
  ushort* Wb    = (ushort*)(ws);                              // 1,703,936 B
  float*  bsum  = (float*)(ws + 1703936);                     // 8,192 B
  ushort* gxF   = (ushort*)(ws + 2097152);                    // 32 MB (chunk)
  ushort* hs0c  = (ushort*)(ws + 2097152 + 33554432);         // 8 MB (chunk)
  float*  hsum  = (float*)(ws + 2097152 + 33554432 + 8388608);// 64 KB
  char*   st    = ws + 2097152 + 33554432 + 8388608 + 65536;
  ushort* hst0  = (ushort*)(st);
  ushort* hst1  = (ushort*)(st + 32768);
  float*  cst0  = (float*)(st + 65536);
  float*  cst1  = (float*)(st + 131072);
  float*  hast  = (float*)(st + 196608);

  hipLaunchKernelGGL(convert_weights, dim3(3328), dim3(256), 0, stream,
                     Wih0, Whh0, Wih1, Whh1, bih0, bhh0, bih1, bhh1, Wb, bsum);

  const ushort* Whh0b = Wb + 65536;
  const ushort* Wih1b = Wb + 327680;
  const ushort* Whh1b = Wb + 589824;

  for (int cidx = 0; cidx < NCH; ++cidx) {
    int t0 = cidx * CH;
    hipLaunchKernelGGL((gemm_gates<0,64>), dim3(CH), dim3(512), 0, stream,
                       (const void*)x, Wb, bsum, gxF, t0);
    hipLaunchKernelGGL((lstm_scan<0>), dim3(4), dim3(512), 0, stream,
                       gxF, Whh0b, hs0c, (float*)nullptr, hst0, cst0, (float*)nullptr, t0);
    hipLaunchKernelGGL((gemm_gates<1,256>), dim3(CH), dim3(512), 0, stream,
                       (const void*)hs0c, Wih1b, bsum + 1024, gxF, t0);
    hipLaunchKernelGGL((lstm_scan<1>), dim3(4), dim3(512), 0, stream,
                       gxF, Whh1b, (ushort*)nullptr, hsum, hst1, cst1, hast, t0);
  }
  hipLaunchKernelGGL(fc_kernel, dim3(1), dim3(640), 0, stream, hsum, Wfc, bfc, out);
}